// Round 2
// baseline (43.493 us; speedup 1.0000x reference)
//
#include <hip/hip_runtime.h>
#include <stdint.h>

// Problem geometry (reference: 128^3 grid, padded to 130^3, cells = 129^3)
constexpr int DIM    = 128;
constexpr int NCX    = 129;
constexpr int NCELLS = NCX * NCX * NCX;            // 2,146,689
constexpr size_t NV_ELEMS = (size_t)NCELLS * 12;   // verts region: 25,760,268 f32
constexpr size_t NT_ELEMS = (size_t)NCELLS * 6;    // tris  region: 12,880,134 f32
// vmask region: NCELLS*4 = 8,586,756 f32 ; total = 47,227,158 f32 elements

__global__ __launch_bounds__(256) void mc_kernel(
    const float* __restrict__ grid,
    const float* __restrict__ deform,
    float*       __restrict__ out)
{
    int tid = blockIdx.x * blockDim.x + threadIdx.x;
    if (tid >= NCELLS) return;

    // cell coords, z fastest (reference meshgrid 'ij' + C-order reshape)
    int z = tid % NCX;
    int t = tid / NCX;
    int y = t % NCX;
    int x = t / NCX;

    // 8 cube corners of padded grid gp[x..x+1][y..y+1][z..z+1];
    // gp[i]=grid[i-1] for i in [1,128], else padding value 1.0 (> isovalue 0)
    float cmin = 3.4e38f, cmax = -3.4e38f;
    #pragma unroll
    for (int dx = 0; dx < 2; ++dx) {
        int i = x + dx - 1;
        bool iok = (unsigned)i < (unsigned)DIM;
        #pragma unroll
        for (int dy = 0; dy < 2; ++dy) {
            int j = y + dy - 1;
            bool jok = (unsigned)j < (unsigned)DIM;
            #pragma unroll
            for (int dz = 0; dz < 2; ++dz) {
                int k = z + dz - 1;
                bool kok = (unsigned)k < (unsigned)DIM;
                float v = 1.0f;
                if (iok && jok && kok)
                    v = grid[((size_t)i * DIM + j) * DIM + k];
                cmin = fminf(cmin, v);
                cmax = fmaxf(cmax, v);
            }
        }
    }
    bool active = (cmin <= 0.0f) && (cmax >= 0.0f);
    float m = active ? 1.0f : 0.0f;

    // deform at padded index (x,y,z): zero in padding region
    float d0 = 0.f, d1 = 0.f, d2 = 0.f;
    {
        int i = x - 1, j = y - 1, k = z - 1;
        if ((unsigned)i < (unsigned)DIM && (unsigned)j < (unsigned)DIM &&
            (unsigned)k < (unsigned)DIM) {
            size_t b = (((size_t)i * DIM + j) * DIM + k) * 3;
            d0 = deform[b]; d1 = deform[b + 1]; d2 = deform[b + 2];
        }
    }
    float cx = (float)x + 0.5f + d0;
    float cy = (float)y + 0.5f + d1;
    float cz = (float)z + 0.5f + d2;

    // post-transform: (v - 1)/128 - 1  ==  v*(1/128) + (-(1/128) - 1)
    constexpr float S = 1.0f / 128.0f;
    constexpr float B = -(1.0f / 128.0f) - 1.0f;
    float ax = fmaf(cx - 0.3f, S, B) * m;   // quad half-extent OFFSET = 0.3
    float bx = fmaf(cx + 0.3f, S, B) * m;
    float ay = fmaf(cy - 0.3f, S, B) * m;
    float by = fmaf(cy + 0.3f, S, B) * m;
    float gz = fmaf(cz,        S, B) * m;

    // --- verts: 12 f32 at out[tid*12] (stride 48 B, 16B-aligned)
    // order: (ax,ay,gz)(bx,ay,gz)(bx,by,gz)(ax,by,gz)
    float4* pv = reinterpret_cast<float4*>(out + (size_t)tid * 12);
    pv[0] = make_float4(ax, ay, gz, bx);
    pv[1] = make_float4(ay, gz, bx, by);
    pv[2] = make_float4(gz, ax, by, gz);

    // --- tris: 6 f32 at out[NV + tid*6] = (4*cell + {0,1,2,0,2,3}) * mask
    float c4 = (float)(tid * 4);            // <= 8,586,752 : exact in f32
    float2* pt = reinterpret_cast<float2*>(out + NV_ELEMS + (size_t)tid * 6);
    pt[0] = make_float2(c4 * m,          (c4 + 1.0f) * m);
    pt[1] = make_float2((c4 + 2.0f) * m,  c4 * m);
    pt[2] = make_float2((c4 + 2.0f) * m, (c4 + 3.0f) * m);

    // --- vmask: 4 identical f32 at out[NV+NT + tid*4] (base 8-mod-16 aligned -> float2)
    float2* pm = reinterpret_cast<float2*>(out + NV_ELEMS + NT_ELEMS + (size_t)tid * 4);
    pm[0] = make_float2(m, m);
    pm[1] = make_float2(m, m);
}

extern "C" void kernel_launch(void* const* d_in, const int* in_sizes, int n_in,
                              void* d_out, int out_size, void* d_ws, size_t ws_size,
                              hipStream_t stream) {
    const float* grid   = (const float*)d_in[0];   // [128,128,128] f32
    const float* deform = (const float*)d_in[1];   // [128,128,128,3] f32
    float* out = (float*)d_out;                    // [verts | tris | vmask] f32 concat

    int blocks = (NCELLS + 255) / 256;
    mc_kernel<<<blocks, 256, 0, stream>>>(grid, deform, out);
}